// Round 7
// baseline (284.148 us; speedup 1.0000x reference)
//
#include <hip/hip_runtime.h>
#include <stdint.h>

// SGRSelector: per-row exact top-K indices, sorted (value desc, idx asc).
// B=256, S=131072, K=16384. Output int32 [B,K] ++ scalar K.
//
// R13: two kernels.
//  K1 capture: 16 chunks/row x 256 thr (grid B*16). Register-batched loads
//    (8 float4 in flight), capture u >= ordered(1.0625) via LDS atomic
//    cursor into an LDS pair buffer (LLVM atomic-optimizer turns the
//    per-lane atomicAdd into 1 DS atomic/wave + mbcnt -- no ballot chain,
//    R11 post-mortem), then ONE global atomic reserves a dense range in the
//    per-row pool; coalesced LDS->global flush. Row swizzle (row = blk % B)
//    keeps a row's chunks on one XCD = K2's L2.
//  K2 finish: 1 block/row x 1024 thr. Hist from pool (all keys b>=BU0),
//    suffix scan -> b1, cursors, heavy list in LDS (<=79 proven), gather
//    pool -> cand buckets (LDS cursors), then in-block sort (R10's proven
//    phases): heavy = 256-digit radix + exact sub-bucket rank; light =
//    one bucket/wave register rank. Fallbacks (pbuf/pool overflow -> full
//    re-read hist + slow gather; captured < K -> low-bin rebuild): exact
//    for any input. Standing caveat (all rounds): bucket > 4096 would clip.

#define S_LEN   131072
#define K_SEL   16384
#define NBINS   8192          // 2^13 buckets on top-13 bits
#define LOWBITS 19
#define IDXMASK 0x1FFFFu      // 17 bits of index
#define CAND_CAP 20480        // sfx[b1] < K + 4096
#define SORT_CAP 4096
#define DIRECT_MAX 256
#define HCAP 96               // heavy buckets <= 20480/257 = 79 (proven)
// capture threshold ordered(1.0625f): P(capture) = 0.1444 one-sided.
#define U0_THRESH 0xBF880000u
#define BU0 (U0_THRESH >> LOWBITS)
// K1 geometry
#define NCH1    16
#define CH1     (S_LEN / NCH1)         // 8192 elems/chunk
#define K1IT    (CH1 / 4 / 256)        // 8 float4 iters/thread
#define PBUF_CAP 2048                  // mean 1183, sigma 32 -> 27 sigma
#define POOL_CAP 24576                 // mean 18930, sigma 127 -> 44 sigma

__device__ __forceinline__ unsigned int ordered_u32(float f) {
  // Monotonic float->uint: larger float => larger uint.
  unsigned int x = __float_as_uint(f);
  unsigned int mask = (unsigned int)((int)x >> 31) | 0x80000000u;
  return x ^ mask;
}

// ---------- K1: high-occupancy capture, LDS-staged, coalesced flush ----------
__global__ __launch_bounds__(256, 4)
void capture_kernel(const float* __restrict__ in,
                    unsigned long long* __restrict__ pool,
                    unsigned int* __restrict__ rowcur,
                    unsigned int* __restrict__ rowflag, int B) {
  const int row   = blockIdx.x % B;          // swizzle: row's chunks share XCD
  const int chunk = blockIdx.x / B;
  const int tid   = threadIdx.x;
  __shared__ unsigned long long pbuf[PBUF_CAP];
  __shared__ unsigned int scnt, sgbase;
  if (tid == 0) scnt = 0;
  __syncthreads();

  const float4* p = (const float4*)(in + (size_t)row * S_LEN + (size_t)chunk * CH1);
  float4 L[K1IT];
#pragma unroll
  for (int it = 0; it < K1IT; ++it) L[it] = p[it * 256 + tid];
#pragma unroll
  for (int it = 0; it < K1IT; ++it) {
    const int idx0 = chunk * CH1 + (it * 256 + tid) * 4;
    const float f[4] = {L[it].x, L[it].y, L[it].z, L[it].w};
#pragma unroll
    for (int e = 0; e < 4; ++e) {
      unsigned int u = ordered_u32(f[e]);
      if (u >= U0_THRESH) {
        unsigned int pos = atomicAdd(&scnt, 1u);   // -> 1 DS atomic/wave (opt)
        if (pos < PBUF_CAP)
          pbuf[pos] = ((unsigned long long)u << 17) |
                      (unsigned long long)(IDXMASK - (unsigned int)(idx0 + e));
      }
    }
  }
  __syncthreads();
  unsigned int cnt = scnt, over = 0;
  if (cnt > PBUF_CAP) { cnt = PBUF_CAP; over = 1; }
  if (tid == 0) sgbase = atomicAdd(&rowcur[row], cnt);  // 1 global atomic/block
  __syncthreads();
  const unsigned int gbase = sgbase;
  unsigned int wc = cnt;
  if (gbase >= POOL_CAP) wc = 0;
  else if (gbase + cnt > POOL_CAP) wc = POOL_CAP - gbase;
  if (tid == 0 && (over || wc < cnt)) rowflag[row] = 1u;
  unsigned long long* dst = pool + (size_t)row * POOL_CAP + gbase;
  for (unsigned int i = tid; i < wc; i += 256) dst[i] = pbuf[i];  // coalesced
}

// Suffix scan over h[NBINS] -> sfx[NBINS]; threshold bucket -> *sb1p
// (sentinel 0xFFFFFFFF if total < K). Uniform control flow; has barriers.
__device__ __forceinline__ void suffix_scan_8k(const unsigned int* h,
                                               unsigned int* sfx,
                                               unsigned int* waveTot,
                                               unsigned int* sb1p,
                                               int tid, int lane, int wave) {
  if (tid == 0) *sb1p = 0xFFFFFFFFu;
  uint4 c0 = *(const uint4*)&h[tid * 8];
  uint4 c1 = *(const uint4*)&h[tid * 8 + 4];
  unsigned int v[8] = {c0.x, c0.y, c0.z, c0.w, c1.x, c1.y, c1.z, c1.w};
#pragma unroll
  for (int s = 6; s >= 0; --s) v[s] += v[s + 1];        // local suffix
  unsigned int tot = v[0];
  unsigned int suf = tot;
#pragma unroll
  for (int d = 1; d < 64; d <<= 1) {
    unsigned int o = __shfl_down(suf, d, 64);
    if (lane + d < 64) suf += o;
  }
  if (lane == 0) waveTot[wave] = suf;
  __syncthreads();
  unsigned int carry = 0;
  for (int w2 = wave + 1; w2 < 16; ++w2) carry += waveTot[w2];
  unsigned int addv = (suf - tot) + carry;              // from all higher threads
  {
    uint4 o0 = make_uint4(v[0] + addv, v[1] + addv, v[2] + addv, v[3] + addv);
    uint4 o1 = make_uint4(v[4] + addv, v[5] + addv, v[6] + addv, v[7] + addv);
    *(uint4*)&sfx[tid * 8]     = o0;
    *(uint4*)&sfx[tid * 8 + 4] = o1;
  }
  __syncthreads();
#pragma unroll
  for (int s = 0; s < 8; ++s) {
    int b = tid * 8 + s;
    unsigned int cur = sfx[b];
    unsigned int nxt = (b + 1 < NBINS) ? sfx[b + 1] : 0u;
    if (cur >= K_SEL && nxt < K_SEL) *sb1p = (unsigned int)b;   // unique b
  }
  __syncthreads();
}

// ---------- K2: hist + scan + gather + in-block sort (1 block/row) ----------
__global__ __launch_bounds__(1024)
void finish_kernel(const float* __restrict__ in,
                   const unsigned long long* __restrict__ pool,
                   const unsigned int* __restrict__ rowcur,
                   const unsigned int* __restrict__ rowflag,
                   unsigned long long* __restrict__ cand,
                   int* __restrict__ out, int B, long long out_size) {
  const int row  = blockIdx.x;
  const int tid  = threadIdx.x;
  const int lane = tid & 63, wave = tid >> 6;           // 16 waves
  __shared__ unsigned int  h[NBINS];                    // counts -> cursors
  __shared__ unsigned int  sfx[NBINS];
  __shared__ unsigned int  skey2[SORT_CAP];             // sort: low-28 key bits
  __shared__ unsigned char sdig2[SORT_CAP];             // sort: 8-bit digit
  __shared__ unsigned int  ssfx[257];
  __shared__ unsigned int  scur[256];
  __shared__ unsigned int  segTot[4];
  __shared__ unsigned int  waveTot[16];
  __shared__ uint2         lheavy[HCAP];
  __shared__ unsigned int  sb1, sbmax, nH;

  for (int i = tid; i < NBINS; i += 1024) h[i] = 0;
  if (tid == 0) nH = 0;
  __syncthreads();

  unsigned int n = rowcur[row];
  const bool flagged = (rowflag[row] != 0u) || (n > POOL_CAP);
  const float4* p = (const float4*)(in + (size_t)row * S_LEN);
  const unsigned long long* pl = pool + (size_t)row * POOL_CAP;

  // ---- hist: fast from pool (all keys have b >= BU0); slow full re-read ----
  if (!flagged) {
    for (unsigned int i = tid; i < n; i += 1024)
      atomicAdd(&h[(unsigned int)(pl[i] >> 36)], 1u);
  } else {
    for (int it = 0; it < 32; ++it) {
      float4 v4 = p[it * 1024 + tid];
      float f[4] = {v4.x, v4.y, v4.z, v4.w};
#pragma unroll
      for (int e = 0; e < 4; ++e)
        atomicAdd(&h[ordered_u32(f[e]) >> LOWBITS], 1u);
    }
  }
  __syncthreads();

  suffix_scan_8k(h, sfx, waveTot, &sb1, tid, lane, wave);
  bool found1 = (sb1 != 0xFFFFFFFFu);
  if (!found1) {                 // captured < K (pathological, only if !flagged)
    for (int it = 0; it < 32; ++it) {
      float4 v4 = p[it * 1024 + tid];
      float f[4] = {v4.x, v4.y, v4.z, v4.w};
#pragma unroll
      for (int e = 0; e < 4; ++e) {
        unsigned int u = ordered_u32(f[e]);
        if (u < U0_THRESH) atomicAdd(&h[u >> LOWBITS], 1u);
      }
    }
    __syncthreads();
    suffix_scan_8k(h, sfx, waveTot, &sb1, tid, lane, wave);
  }
  const unsigned int b1 = sb1;                          // always found now
  const bool fast = found1 && !flagged;

  // ---- cursors h[b]=start, heavy list, bmax ----
  for (int i = tid; i < NBINS; i += 1024) {
    unsigned int end   = sfx[i];
    unsigned int start = (i + 1 < NBINS) ? sfx[i + 1] : 0u;
    h[i] = start;
    if (end > 0u && start == 0u) sbmax = (unsigned int)i;   // highest nonempty
    if ((unsigned int)i >= b1) {
      unsigned int c2 = end - start;
      if (c2 > DIRECT_MAX) {
        unsigned int p2 = atomicAdd(&nH, 1u);
        if (p2 < HCAP) lheavy[p2] = make_uint2(start, end);
      }
    }
  }
  __syncthreads();

  // ---- gather into cand buckets ----
  unsigned long long* c = cand + (size_t)row * CAND_CAP;
  if (fast) {
    for (unsigned int i = tid; i < n; i += 1024) {
      unsigned long long k = pl[i];
      unsigned int b = (unsigned int)(k >> 36);
      if (b >= b1) {
        unsigned int pos = atomicAdd(&h[b], 1u);
        if (pos < CAND_CAP) c[pos] = k;
      }
    }
  } else {
    for (int it = 0; it < 32; ++it) {
      int i4 = it * 1024 + tid;
      float4 v4 = p[i4];
      int idx0 = i4 * 4;
      float f[4] = {v4.x, v4.y, v4.z, v4.w};
#pragma unroll
      for (int e = 0; e < 4; ++e) {
        unsigned int u = ordered_u32(f[e]);
        unsigned int b = u >> LOWBITS;
        if (b >= b1) {
          unsigned int pos = atomicAdd(&h[b], 1u);
          unsigned long long key =
              ((unsigned long long)u << 17) |
              (unsigned long long)(IDXMASK - (unsigned int)(idx0 + e));
          if (pos < CAND_CAP) c[pos] = key;
        }
      }
    }
  }
  if (row == 0 && tid == 0) {
    long long pos = (long long)B * K_SEL;
    if (pos < out_size) out[pos] = K_SEL;
  }
  __syncthreads();             // cand visible in-block (R10 precedent, passed)

  int* orow = out + (size_t)row * K_SEL;

  // ---- heavy buckets (count > 256): whole block per bucket (R10 proven) ----
  const unsigned int nHv = (nH < HCAP) ? nH : HCAP;
  for (unsigned int hi = 0; hi < nHv; ++hi) {
    const uint2 be = lheavy[hi];
    const unsigned int start = be.x;
    unsigned int count = be.y - be.x;
    if (count > SORT_CAP) count = SORT_CAP;             // never for this input
    const unsigned long long* cc = c + start;

    unsigned long long me[4];                           // stage: 1 global read
#pragma unroll
    for (int j = 0; j < 4; ++j) {
      unsigned int i = (unsigned int)tid + 1024u * j;
      me[j] = (i < count) ? cc[i] : 0ull;
    }
    if (tid < 256) scur[tid] = 0;
    __syncthreads();
#pragma unroll
    for (int j = 0; j < 4; ++j) {
      unsigned int i = (unsigned int)tid + 1024u * j;
      if (i < count) atomicAdd(&scur[(unsigned int)(me[j] >> 28) & 255u], 1u);
    }
    __syncthreads();
    unsigned int sufH = 0;
    if (tid < 256) {                                    // 256-digit suffix scan
      sufH = scur[tid];
#pragma unroll
      for (int d = 1; d < 64; d <<= 1) {
        unsigned int o = __shfl_down(sufH, d, 64);
        if (lane + d < 64) sufH += o;
      }
      if (lane == 0) segTot[wave] = sufH;
    }
    __syncthreads();
    if (tid < 256) {
      unsigned int carry = 0;
      for (int w2 = wave + 1; w2 < 4; ++w2) carry += segTot[w2];
      ssfx[tid] = sufH + carry;                         // # elems digit >= tid
      if (tid == 0) ssfx[256] = 0;
    }
    __syncthreads();
    if (tid < 256) scur[tid] = ssfx[tid + 1];           // digit start cursor
    __syncthreads();
#pragma unroll
    for (int j = 0; j < 4; ++j) {                       // scatter by digit
      unsigned int i = (unsigned int)tid + 1024u * j;
      if (i < count) {
        unsigned long long k = me[j];
        unsigned int d = (unsigned int)(k >> 28) & 255u;
        unsigned int p2 = atomicAdd(&scur[d], 1u);
        skey2[p2] = (unsigned int)k & 0x0FFFFFFFu;
        sdig2[p2] = (unsigned char)d;
      }
    }
    __syncthreads();
    for (unsigned int p2 = tid; p2 < count; p2 += 1024) {   // exact rank
      unsigned int k = skey2[p2];
      unsigned int d = sdig2[p2];
      unsigned int lo = ssfx[d + 1], hi2 = ssfx[d];
      unsigned int r = 0;
      for (unsigned int q = lo; q < hi2; ++q) r += (skey2[q] > k) ? 1u : 0u;
      unsigned int pos = start + lo + r;
      if (pos < K_SEL)
        orow[pos] = (int)(IDXMASK - (k & IDXMASK));
    }
    __syncthreads();
  }

  // ---- light buckets (1..256): one bucket per wave, no barriers ----
  const unsigned int bmaxv = sbmax;
  for (unsigned int b = b1 + (unsigned int)wave; b <= bmaxv; b += 16u) {
    unsigned int end   = sfx[b];
    unsigned int start = (b + 1 < NBINS) ? sfx[b + 1] : 0u;
    unsigned int count = end - start;
    if (count == 0u || count > DIRECT_MAX) continue;
    const unsigned long long* cc = c + start;
    if (count <= 64) {                                  // 1 key/lane
      unsigned long long me = ((unsigned int)lane < count) ? cc[lane] : 0ull;
      unsigned int r = 0;
      for (int l = 0; l < 64; ++l)
        r += (__shfl(me, l, 64) > me) ? 1u : 0u;
      if ((unsigned int)lane < count) {
        unsigned int pos = start + r;
        if (pos < K_SEL)
          orow[pos] = (int)(IDXMASK - ((unsigned int)me & IDXMASK));
      }
    } else if (count <= 128) {                          // 2 keys/lane
      unsigned long long me[2];
#pragma unroll
      for (int e = 0; e < 2; ++e) {
        unsigned int i = (unsigned int)lane + 64u * e;
        me[e] = (i < count) ? cc[i] : 0ull;
      }
      unsigned int r[2] = {0u, 0u};
#pragma unroll
      for (int e = 0; e < 2; ++e) {
        for (int l = 0; l < 64; ++l) {
          unsigned long long kj = __shfl(me[e], l, 64);
#pragma unroll
          for (int e2 = 0; e2 < 2; ++e2) r[e2] += (kj > me[e2]) ? 1u : 0u;
        }
      }
#pragma unroll
      for (int e = 0; e < 2; ++e) {
        unsigned int i = (unsigned int)lane + 64u * e;
        if (i < count) {
          unsigned int pos = start + r[e];
          if (pos < K_SEL)
            orow[pos] = (int)(IDXMASK - ((unsigned int)me[e] & IDXMASK));
        }
      }
    } else {                                            // 4 keys/lane
      unsigned long long me[4];
#pragma unroll
      for (int e = 0; e < 4; ++e) {
        unsigned int i = (unsigned int)lane + 64u * e;
        me[e] = (i < count) ? cc[i] : 0ull;
      }
      unsigned int r[4] = {0u, 0u, 0u, 0u};
#pragma unroll
      for (int e = 0; e < 4; ++e) {
        for (int l = 0; l < 64; ++l) {
          unsigned long long kj = __shfl(me[e], l, 64);
#pragma unroll
          for (int e2 = 0; e2 < 4; ++e2) r[e2] += (kj > me[e2]) ? 1u : 0u;
        }
      }
#pragma unroll
      for (int e = 0; e < 4; ++e) {
        unsigned int i = (unsigned int)lane + 64u * e;
        if (i < count) {
          unsigned int pos = start + r[e];
          if (pos < K_SEL)
            orow[pos] = (int)(IDXMASK - ((unsigned int)me[e] & IDXMASK));
        }
      }
    }
  }
}

extern "C" void kernel_launch(void* const* d_in, const int* in_sizes, int n_in,
                              void* d_out, int out_size, void* d_ws, size_t ws_size,
                              hipStream_t stream) {
  const float* importance = (const float*)d_in[0];
  int B = in_sizes[0] / S_LEN;
  if (B < 1) B = 1;
  (void)n_in; (void)ws_size;

  size_t poolBytes = (size_t)B * POOL_CAP * sizeof(unsigned long long); // 50.3 MB
  size_t candBytes = (size_t)B * CAND_CAP * sizeof(unsigned long long); // 41.9 MB
  char* base = (char*)d_ws;
  unsigned long long* pool = (unsigned long long*)base;
  unsigned long long* cand = (unsigned long long*)(base + poolBytes);
  unsigned int* rowcur     = (unsigned int*)(base + poolBytes + candBytes);
  unsigned int* rowflag    = rowcur + B;
  int* out = (int*)d_out;

  hipMemsetAsync(rowcur, 0, 2 * (size_t)B * sizeof(unsigned int), stream);
  capture_kernel<<<dim3(B * NCH1), dim3(256), 0, stream>>>(
      importance, pool, rowcur, rowflag, B);
  finish_kernel<<<dim3(B), dim3(1024), 0, stream>>>(
      importance, pool, rowcur, rowflag, cand, out, B, (long long)out_size);
}

// Round 9
// 265.880 us; speedup vs baseline: 1.0687x; 1.0687x over previous
//
#include <hip/hip_runtime.h>
#include <stdint.h>

// SGRSelector: per-row exact top-K indices, sorted (value desc, idx asc).
// B=256, S=131072, K=16384. Output int32 [B,K] ++ scalar K.
//
// R15 = exact restore of R9 (best verified: 265.9 us, Round-3 bench).
// R14's inline-asm async loads corrupted data (pending-VMEM dest registers
// moved by regalloc between issue and waitcnt) -- that line is abandoned.
// R9 structure: phase-1 streams the row capturing b >= BU0 (ballot-compacted
// coalesced per-wave segments) with the LDS histogram restricted to captured
// elements; suffix scan -> b1; worklists; gather from L2-hot segments.
// Fallbacks (captured < K -> low-bin rebuild + rescan + slow gather) keep
// exactness for any input. Sort: register-staged heavy + wave-per-light.

#define S_LEN   131072
#define K_SEL   16384
#define NBINS   8192          // 2^13 buckets on top-13 bits
#define LOWBITS 19
#define IDXMASK 0x1FFFFu      // 17 bits of index
#define CAND_CAP 20480        // >= suffix[b1] ~ 18100 (max bucket <= 4096, R3)
#define SORT_CAP 4096
#define DIRECT_MAX 256
#define WL_PER_ROW 2048
#define D_GRID  2048
#define HCAP 256
#define LCAP 512
#define NWAVE 16
#define PC_WAVE 1664          // per-wave capture cap (mean ~1300, sigma ~33)
#define NITER (S_LEN / 4 / 1024)   // 32 float4 iters per thread
// bucket of ordered(+1.0f): all-rows threshold ~1.15 sits 2-3 buckets above.
#define U0_THRESH 0xBF800000u
#define BU0 (U0_THRESH >> LOWBITS)

__device__ __forceinline__ unsigned int ordered_u32(float f) {
  // Monotonic float->uint: larger float => larger uint.
  unsigned int x = __float_as_uint(f);
  unsigned int mask = (unsigned int)((int)x >> 31) | 0x80000000u;
  return x ^ mask;
}

// Suffix scan over h[NBINS] -> sfx[NBINS]; threshold bucket -> *sb1p
// (sentinel 0xFFFFFFFF if total < K). Uniform control flow; has barriers.
__device__ __forceinline__ void suffix_scan_8k(const unsigned int* h,
                                               unsigned int* sfx,
                                               unsigned int* waveTot,
                                               unsigned int* sb1p,
                                               int tid, int lane, int wave) {
  if (tid == 0) *sb1p = 0xFFFFFFFFu;
  uint4 c0 = *(const uint4*)&h[tid * 8];
  uint4 c1 = *(const uint4*)&h[tid * 8 + 4];
  unsigned int v[8] = {c0.x, c0.y, c0.z, c0.w, c1.x, c1.y, c1.z, c1.w};
#pragma unroll
  for (int s = 6; s >= 0; --s) v[s] += v[s + 1];        // local suffix
  unsigned int tot = v[0];
  unsigned int suf = tot;
#pragma unroll
  for (int d = 1; d < 64; d <<= 1) {
    unsigned int o = __shfl_down(suf, d, 64);
    if (lane + d < 64) suf += o;
  }
  if (lane == 0) waveTot[wave] = suf;
  __syncthreads();
  unsigned int carry = 0;
  for (int w2 = wave + 1; w2 < NWAVE; ++w2) carry += waveTot[w2];
  unsigned int addv = (suf - tot) + carry;              // from all higher threads
  {
    uint4 o0 = make_uint4(v[0] + addv, v[1] + addv, v[2] + addv, v[3] + addv);
    uint4 o1 = make_uint4(v[4] + addv, v[5] + addv, v[6] + addv, v[7] + addv);
    *(uint4*)&sfx[tid * 8]     = o0;
    *(uint4*)&sfx[tid * 8 + 4] = o1;
  }
  __syncthreads();
#pragma unroll
  for (int s = 0; s < 8; ++s) {
    int b = tid * 8 + s;
    unsigned int cur = sfx[b];
    unsigned int nxt = (b + 1 < NBINS) ? sfx[b + 1] : 0u;
    if (cur >= K_SEL && nxt < K_SEL) *sb1p = (unsigned int)b;   // unique b
  }
  __syncthreads();
}

// ---------- fused select: capture + hist(captured) + scan + worklists + gather ----------
__global__ __launch_bounds__(1024)
void select_kernel(const float* __restrict__ in,
                   unsigned long long* __restrict__ pairs,
                   unsigned long long* __restrict__ cand,
                   uint4* __restrict__ wl, unsigned int* __restrict__ ctrs,
                   unsigned int wlHalf, int* __restrict__ out,
                   int B, long long out_size) {
  const int row  = blockIdx.x;
  const int tid  = threadIdx.x;
  const int lane = tid & 63, wave = tid >> 6;           // 16 waves
  __shared__ unsigned int h[NBINS];                     // counts -> cursors
  __shared__ unsigned int sfx[NBINS];
  __shared__ unsigned int waveTot[NWAVE];
  __shared__ unsigned int wcnt[NWAVE];
  __shared__ unsigned int sb1, nH, nL, gHs, gLs;
  __shared__ uint2 lheavy[HCAP];
  __shared__ uint2 llight[LCAP];

  for (int i = tid; i < NBINS; i += 1024) h[i] = 0;
  if (tid == 0) { nH = 0; nL = 0; }
  __syncthreads();

  // ---- phase 1: stream row; capture + histogram ONLY b >= BU0 (~16%) ----
  const float4* p = (const float4*)(in + (size_t)row * S_LEN);
  unsigned long long* seg = pairs + ((size_t)row * NWAVE + wave) * PC_WAVE;
  unsigned int base = 0;                                // wave-uniform cursor
  const unsigned long long lmask = (1ull << lane) - 1ull;
#pragma unroll 8
  for (int it = 0; it < NITER; ++it) {
    int i4 = it * 1024 + tid;
    float4 v4 = p[i4];
    int idx0 = i4 * 4;
    float f[4] = {v4.x, v4.y, v4.z, v4.w};
#pragma unroll
    for (int e = 0; e < 4; ++e) {
      unsigned int u = ordered_u32(f[e]);
      unsigned int b = u >> LOWBITS;
      bool pred = (b >= BU0);
      unsigned long long m = __ballot(pred);
      if (pred) {
        atomicAdd(&h[b], 1u);
        unsigned int pos = base + (unsigned int)__popcll(m & lmask);
        unsigned long long key =                        // 49-bit key, unique
            ((unsigned long long)u << 17) |
            (unsigned long long)(IDXMASK - (unsigned int)(idx0 + e));
        if (pos < PC_WAVE) seg[pos] = key;
      }
      base += (unsigned int)__popcll(m);
    }
  }
  if (lane == 0) wcnt[wave] = base;
  __syncthreads();

  // ---- phase 2: suffix scan (bins < BU0 are zero => flat; crossing >= BU0) ----
  suffix_scan_8k(h, sfx, waveTot, &sb1, tid, lane, wave);
  bool found1 = (sb1 != 0xFFFFFFFFu);
  if (!found1) {
    // total captured < K (pathological input): histogram the LOW bins exactly
    // (high bins already exact from phase 1), rescan. Slow gather below.
#pragma unroll 4
    for (int it = 0; it < NITER; ++it) {
      float4 v4 = p[it * 1024 + tid];
      float f[4] = {v4.x, v4.y, v4.z, v4.w};
#pragma unroll
      for (int e = 0; e < 4; ++e) {
        unsigned int b = ordered_u32(f[e]) >> LOWBITS;
        if (b < BU0) atomicAdd(&h[b], 1u);
      }
    }
    __syncthreads();
    suffix_scan_8k(h, sfx, waveTot, &sb1, tid, lane, wave);
  }
  const unsigned int b1 = sb1;                          // always found now

  // ---- phase 3: cursors (h[b] = bucket start) + local worklists ----
  for (int i = tid; i < NBINS; i += 1024) {
    unsigned int end   = sfx[i];
    unsigned int start = (i + 1 < NBINS) ? sfx[i + 1] : 0u;
    h[i] = start;                                       // gather cursor
    if ((unsigned int)i >= b1) {
      unsigned int cnt = end - start;
      if (cnt) {
        if (cnt > DIRECT_MAX) {
          unsigned int p2 = atomicAdd(&nH, 1u);
          if (p2 < HCAP) lheavy[p2] = make_uint2(start, end);
          else {                                        // overflow fallback
            unsigned int g = atomicAdd(&ctrs[0], 1u);
            if (g < wlHalf) wl[2 * wlHalf - 1 - g] = make_uint4((unsigned int)row, start, end, 0u);
          }
        } else {
          unsigned int p2 = atomicAdd(&nL, 1u);
          if (p2 < LCAP) llight[p2] = make_uint2(start, end);
          else {
            unsigned int g = atomicAdd(&ctrs[1], 1u);
            if (g < wlHalf) wl[g] = make_uint4((unsigned int)row, start, end, 0u);
          }
        }
      }
    }
  }
  __syncthreads();
  if (tid == 0) {                                       // bulk reserve: 2 atomics/block
    gHs = atomicAdd(&ctrs[0], nH < HCAP ? nH : HCAP);
    gLs = atomicAdd(&ctrs[1], nL < LCAP ? nL : LCAP);
  }
  __syncthreads();
  {
    unsigned int hN = nH < HCAP ? nH : HCAP;
    unsigned int lN = nL < LCAP ? nL : LCAP;
    for (unsigned int i = tid; i < hN; i += 1024) {
      uint2 e = lheavy[i]; unsigned int pos = gHs + i;
      if (pos < wlHalf) wl[2 * wlHalf - 1 - pos] = make_uint4((unsigned int)row, e.x, e.y, 0u);
    }
    for (unsigned int i = tid; i < lN; i += 1024) {
      uint2 e = llight[i]; unsigned int pos = gLs + i;
      if (pos < wlHalf) wl[pos] = make_uint4((unsigned int)row, e.x, e.y, 0u);
    }
  }

  // ---- phase 4: gather. Fast: scan captured pairs (L2-hot). Slow: re-read row. ----
  bool fast = found1;
  for (int w2 = 0; w2 < NWAVE; ++w2) fast = fast && (wcnt[w2] <= PC_WAVE);
  unsigned long long* c = cand + (size_t)row * CAND_CAP;
  if (fast) {
    const unsigned int myN = wcnt[wave];                // each wave scans its own segment
    for (unsigned int i = (unsigned int)lane; i < myN; i += 64u) {
      unsigned long long k = seg[i];
      unsigned int b = (unsigned int)(k >> 36);
      if (b >= b1) {
        unsigned int pos = atomicAdd(&h[b], 1u);
        if (pos < CAND_CAP) c[pos] = k;
      }
    }
  } else {
#pragma unroll 4
    for (int it = 0; it < NITER; ++it) {
      int i4 = it * 1024 + tid;
      float4 v4 = p[i4];
      int idx0 = i4 * 4;
      float f[4] = {v4.x, v4.y, v4.z, v4.w};
#pragma unroll
      for (int e = 0; e < 4; ++e) {
        unsigned int u = ordered_u32(f[e]);
        unsigned int b = u >> LOWBITS;
        if (b >= b1) {
          unsigned int pos = atomicAdd(&h[b], 1u);
          unsigned long long key =
              ((unsigned long long)u << 17) |
              (unsigned long long)(IDXMASK - (unsigned int)(idx0 + e));
          if (pos < CAND_CAP) c[pos] = key;
        }
      }
    }
  }
  if (row == 0 && tid == 0) {
    long long pos = (long long)B * K_SEL;
    if (pos < out_size) out[pos] = K_SEL;
  }
}

// ---------- D: static-stride per-bucket exact ranking ----------
__global__ __launch_bounds__(256)
void sort_kernel(const uint4* __restrict__ wl, const unsigned int* __restrict__ ctrs,
                 unsigned int wlHalf, const unsigned long long* __restrict__ cand,
                 int* __restrict__ out) {
  const int tid  = threadIdx.x;            // 256 threads, 4 waves
  const int lane = tid & 63, wave = tid >> 6;
  __shared__ unsigned int   skey2[SORT_CAP];   // 16 KiB: low-28 key bits
  __shared__ unsigned char  sdig2[SORT_CAP];   //  4 KiB: 8-bit digit
  __shared__ unsigned int   ssfx[257];
  __shared__ unsigned int   scur[256];
  __shared__ unsigned int   segTot[4];
  unsigned int nHeavy = ctrs[0]; if (nHeavy > wlHalf) nHeavy = wlHalf;
  unsigned int nLight = ctrs[1]; if (nLight > wlHalf) nLight = wlHalf;

  // ---- heavy phase (count > 256): register-staged keys, ONE global read ----
  for (unsigned int w = blockIdx.x; w < nHeavy; w += gridDim.x) {
    const uint4 it = wl[2 * wlHalf - 1 - w];
    const unsigned int row = it.x, start = it.y;
    unsigned int count = it.z - start;
    if (count > SORT_CAP) count = SORT_CAP;      // proven never hit (R3)
    const unsigned long long* c = cand + (size_t)row * CAND_CAP + start;
    int* orow = out + (size_t)row * K_SEL;

    // stage up to 16 keys/thread in registers (static indexing)
    unsigned long long me[16];
#pragma unroll
    for (int j = 0; j < 16; ++j) {
      unsigned int i = (unsigned int)tid + 256u * j;
      me[j] = (i < count) ? c[i] : 0ull;
    }
    scur[tid] = 0;
    __syncthreads();
#pragma unroll
    for (int j = 0; j < 16; ++j) {
      unsigned int i = (unsigned int)tid + 256u * j;
      if (i < count) atomicAdd(&scur[(unsigned int)(me[j] >> 28) & 255u], 1u);
    }
    __syncthreads();
    // 256-digit suffix scan via shuffles (digit = tid)
    unsigned int cnt = scur[tid];
    unsigned int suf = cnt;
#pragma unroll
    for (int d = 1; d < 64; d <<= 1) {
      unsigned int o = __shfl_down(suf, d, 64);
      if (lane + d < 64) suf += o;
    }
    if (lane == 0) segTot[wave] = suf;
    __syncthreads();
    unsigned int carry = 0;
    for (int w2 = wave + 1; w2 < 4; ++w2) carry += segTot[w2];
    ssfx[tid] = suf + carry;                     // # elements with digit >= tid
    if (tid == 0) ssfx[256] = 0;
    __syncthreads();
    scur[tid] = ssfx[tid + 1];                   // digit range start cursor
    __syncthreads();
    // scatter by digit from registers; keep only low-28 bits + digit
#pragma unroll
    for (int j = 0; j < 16; ++j) {
      unsigned int i = (unsigned int)tid + 256u * j;
      if (i < count) {
        unsigned long long k = me[j];
        unsigned int d = (unsigned int)(k >> 28) & 255u;
        unsigned int p = atomicAdd(&scur[d], 1u);
        skey2[p] = (unsigned int)k & 0x0FFFFFFFu;
        sdig2[p] = (unsigned char)d;
      }
    }
    __syncthreads();
    // exact rank within sub-bucket (keys unique; same digit -> low28 decides)
    for (unsigned int p = tid; p < count; p += 256) {
      unsigned int k = skey2[p];
      unsigned int d = sdig2[p];
      unsigned int lo = ssfx[d + 1], hi = ssfx[d];
      unsigned int r = 0;
      for (unsigned int q = lo; q < hi; ++q) r += (skey2[q] > k) ? 1u : 0u;
      unsigned int pos = start + lo + r;
      if (pos < K_SEL)
        orow[pos] = (int)(IDXMASK - (k & IDXMASK));
    }
    __syncthreads();
  }

  // ---- light phase (count <= 256): one item per WAVE, register-only rank ----
  for (unsigned int w = blockIdx.x * 4u + (unsigned int)wave; w < nLight;
       w += gridDim.x * 4u) {
    const uint4 it = wl[w];
    const unsigned int row = it.x, start = it.y;
    const unsigned int count = it.z - start;
    const unsigned long long* c = cand + (size_t)row * CAND_CAP + start;
    int* orow = out + (size_t)row * K_SEL;
    if (count <= 64) {                           // 1 key/lane
      unsigned long long me = ((unsigned int)lane < count) ? c[lane] : 0ull;
      unsigned int r = 0;
      for (int l = 0; l < 64; ++l)
        r += (__shfl(me, l, 64) > me) ? 1u : 0u;
      if ((unsigned int)lane < count) {
        unsigned int pos = start + r;
        if (pos < K_SEL)
          orow[pos] = (int)(IDXMASK - ((unsigned int)me & IDXMASK));
      }
    } else if (count <= 128) {                   // 2 keys/lane
      unsigned long long me[2];
#pragma unroll
      for (int e = 0; e < 2; ++e) {
        unsigned int i = (unsigned int)lane + 64u * e;
        me[e] = (i < count) ? c[i] : 0ull;
      }
      unsigned int r[2] = {0u, 0u};
#pragma unroll
      for (int e = 0; e < 2; ++e) {
        for (int l = 0; l < 64; ++l) {
          unsigned long long kj = __shfl(me[e], l, 64);
#pragma unroll
          for (int e2 = 0; e2 < 2; ++e2) r[e2] += (kj > me[e2]) ? 1u : 0u;
        }
      }
#pragma unroll
      for (int e = 0; e < 2; ++e) {
        unsigned int i = (unsigned int)lane + 64u * e;
        if (i < count) {
          unsigned int pos = start + r[e];
          if (pos < K_SEL)
            orow[pos] = (int)(IDXMASK - ((unsigned int)me[e] & IDXMASK));
        }
      }
    } else {                                     // 4 keys/lane
      unsigned long long me[4];
#pragma unroll
      for (int e = 0; e < 4; ++e) {
        unsigned int i = (unsigned int)lane + 64u * e;
        me[e] = (i < count) ? c[i] : 0ull;
      }
      unsigned int r[4] = {0u, 0u, 0u, 0u};
#pragma unroll
      for (int e = 0; e < 4; ++e) {
        for (int l = 0; l < 64; ++l) {
          unsigned long long kj = __shfl(me[e], l, 64);
#pragma unroll
          for (int e2 = 0; e2 < 4; ++e2) r[e2] += (kj > me[e2]) ? 1u : 0u;
        }
      }
#pragma unroll
      for (int e = 0; e < 4; ++e) {
        unsigned int i = (unsigned int)lane + 64u * e;
        if (i < count) {
          unsigned int pos = start + r[e];
          if (pos < K_SEL)
            orow[pos] = (int)(IDXMASK - ((unsigned int)me[e] & IDXMASK));
        }
      }
    }
  }
}

extern "C" void kernel_launch(void* const* d_in, const int* in_sizes, int n_in,
                              void* d_out, int out_size, void* d_ws, size_t ws_size,
                              hipStream_t stream) {
  const float* importance = (const float*)d_in[0];
  int B = in_sizes[0] / S_LEN;
  if (B < 1) B = 1;
  (void)n_in; (void)ws_size;

  const unsigned int wlCap  = (unsigned int)B * WL_PER_ROW;   // total uint4 slots
  const unsigned int wlHalf = wlCap / 2;
  size_t pairBytes = (size_t)B * NWAVE * PC_WAVE * sizeof(unsigned long long); // 54.5 MB
  size_t candBytes = (size_t)B * CAND_CAP * sizeof(unsigned long long);        // 40 MB
  size_t wlBytes   = (size_t)wlCap * sizeof(uint4);                            //  8 MB
  char* base = (char*)d_ws;
  unsigned long long* pairs = (unsigned long long*)base;
  unsigned long long* cand  = (unsigned long long*)(base + pairBytes);
  uint4* wl                 = (uint4*)(base + pairBytes + candBytes);
  unsigned int* ctrs        = (unsigned int*)(base + pairBytes + candBytes + wlBytes);
  int* out = (int*)d_out;

  hipMemsetAsync(ctrs, 0, 4 * sizeof(unsigned int), stream);
  select_kernel<<<dim3(B),      dim3(1024), 0, stream>>>(
      importance, pairs, cand, wl, ctrs, wlHalf, out, B, (long long)out_size);
  sort_kernel  <<<dim3(D_GRID), dim3(256),  0, stream>>>(wl, ctrs, wlHalf, cand, out);
}